// Round 3
// baseline (11495.064 us; speedup 1.0000x reference)
//
#include <hip/hip_runtime.h>
#include <hip/hip_bf16.h>
#include <math.h>

// Problem constants
constexpr int kB  = 8;
constexpr int kS  = 256;
constexpr int kH  = 768;
constexpr int kNL = 12;
constexpr int kNH = 12;
constexpr int kFF = 3072;
constexpr int kC  = 9;
constexpr int kDH = 64;
constexpr int kM  = kB * kS;   // 2048 tokens

// ---------------------------------------------------------------------------
// Embedding gather: h[tok,c] = word_emb[x[tok],c] + pos_emb[tok%S,c] + type_emb[c]
// ---------------------------------------------------------------------------
__global__ __launch_bounds__(256) void embed_kernel(
    const int* __restrict__ x, const float* __restrict__ we,
    const float* __restrict__ pe, const float* __restrict__ te,
    float* __restrict__ h) {
  int tok = blockIdx.x;
  int wid = x[tok];
  int s = tok % kS;
  for (int c = threadIdx.x; c < kH; c += 256) {
    h[(size_t)tok * kH + c] = we[(size_t)wid * kH + c] + pe[s * kH + c] + te[c];
  }
}

// ---------------------------------------------------------------------------
// Fused (optional residual add) + LayerNorm, in-place capable.
// One block (256 threads) per token; H=768 = 3 elems/thread.
// ---------------------------------------------------------------------------
__global__ __launch_bounds__(256) void addln_kernel(
    const float* __restrict__ hin, const float* __restrict__ res,
    const float* __restrict__ w, const float* __restrict__ b,
    float* __restrict__ hout) {
  int tok = blockIdx.x, tid = threadIdx.x;
  __shared__ float red[8];
  float vals[3];
  float s = 0.f, s2 = 0.f;
#pragma unroll
  for (int j = 0; j < 3; j++) {
    int c = tid + j * 256;
    float v = hin[(size_t)tok * kH + c];
    if (res) v += res[(size_t)tok * kH + c];
    vals[j] = v;
    s += v;
    s2 += v * v;
  }
#pragma unroll
  for (int o = 32; o > 0; o >>= 1) {
    s  += __shfl_down(s, o, 64);
    s2 += __shfl_down(s2, o, 64);
  }
  int lane = tid & 63, wv = tid >> 6;
  if (lane == 0) { red[wv] = s; red[4 + wv] = s2; }
  __syncthreads();
  float sum   = red[0] + red[1] + red[2] + red[3];
  float sumsq = red[4] + red[5] + red[6] + red[7];
  float mean = sum / kH;
  float var  = sumsq / kH - mean * mean;
  float inv  = rsqrtf(var + 1e-12f);
#pragma unroll
  for (int j = 0; j < 3; j++) {
    int c = tid + j * 256;
    hout[(size_t)tok * kH + c] = (vals[j] - mean) * inv * w[c] + b[c];
  }
}

// ---------------------------------------------------------------------------
// Tiled GEMM: C[M,N] = A[M,K] @ B[K,N] + bias, opt. GELU. All fp32.
// 64x64 tile, BK=16, 256 threads, 4x4 per thread. Dims must divide tiles.
// ---------------------------------------------------------------------------
template <int ACT>
__global__ __launch_bounds__(256) void gemm_kernel(
    const float* __restrict__ A, const float* __restrict__ Bw,
    const float* __restrict__ bias, float* __restrict__ Cc,
    int Mdim, int N, int K) {
  __shared__ float As[16][68];
  __shared__ float Bs[16][68];
  int tid = threadIdx.x;
  int bx = blockIdx.x, by = blockIdx.y;
  int tx = tid & 15, ty = tid >> 4;
  float acc[4][4] = {};
  const float* Ab = A + (size_t)(by * 64) * K;
  const float* Bb = Bw + bx * 64;

  for (int kt = 0; kt < K; kt += 16) {
    // Stage A tile (64 rows x 16 k), transposed into As[k][m]
#pragma unroll
    for (int j = 0; j < 4; j++) {
      int idx = tid + j * 256;
      int m = idx >> 4, kk = idx & 15;
      As[kk][m] = Ab[(size_t)m * K + kt + kk];
    }
    // Stage B tile (16 k x 64 n)
#pragma unroll
    for (int j = 0; j < 4; j++) {
      int idx = tid + j * 256;
      int kk = idx >> 6, n = idx & 63;
      Bs[kk][n] = Bb[(size_t)(kt + kk) * N + n];
    }
    __syncthreads();
#pragma unroll
    for (int kk = 0; kk < 16; kk++) {
      float a[4], bb[4];
#pragma unroll
      for (int i = 0; i < 4; i++) a[i] = As[kk][ty * 4 + i];
#pragma unroll
      for (int j = 0; j < 4; j++) bb[j] = Bs[kk][tx * 4 + j];
#pragma unroll
      for (int i = 0; i < 4; i++)
#pragma unroll
        for (int j = 0; j < 4; j++) acc[i][j] += a[i] * bb[j];
    }
    __syncthreads();
  }

#pragma unroll
  for (int i = 0; i < 4; i++) {
    int m = by * 64 + ty * 4 + i;
#pragma unroll
    for (int j = 0; j < 4; j++) {
      int n = bx * 64 + tx * 4 + j;
      float cv = acc[i][j] + bias[n];
      if (ACT == 1) {  // tanh-approx GELU (jax.nn.gelu default)
        float xx = cv;
        float inner = 0.7978845608028654f * (xx + 0.044715f * xx * xx * xx);
        cv = 0.5f * xx * (1.0f + tanhf(inner));
      }
      Cc[(size_t)m * N + n] = cv;
    }
  }
}

// ---------------------------------------------------------------------------
// Fused attention for one (batch, head, query row): scores -> softmax -> PV.
// grid = (S, NH, B), 256 threads (one per key).
// ---------------------------------------------------------------------------
__global__ __launch_bounds__(256) void attn_kernel(
    const float* __restrict__ q, const float* __restrict__ k,
    const float* __restrict__ v, float* __restrict__ ctx) {
  int qi = blockIdx.x, hh = blockIdx.y, bb = blockIdx.z;
  int tid = threadIdx.x;
  __shared__ float qv[kDH];
  __shared__ float sc[kS];
  __shared__ float red[8];
  __shared__ float part[256];

  if (tid < kDH) qv[tid] = q[(size_t)(bb * kS + qi) * kH + hh * kDH + tid];
  __syncthreads();

  const float* krow = k + (size_t)(bb * kS + tid) * kH + hh * kDH;
  float dot = 0.f;
#pragma unroll 8
  for (int d = 0; d < kDH; d++) dot += qv[d] * krow[d];
  dot *= 0.125f;  // 1/sqrt(64)

  // block max
  float mv = dot;
#pragma unroll
  for (int o = 32; o > 0; o >>= 1) mv = fmaxf(mv, __shfl_down(mv, o, 64));
  int lane = tid & 63, wv = tid >> 6;
  if (lane == 0) red[wv] = mv;
  __syncthreads();
  mv = fmaxf(fmaxf(red[0], red[1]), fmaxf(red[2], red[3]));

  float p = expf(dot - mv);
  sc[tid] = p;
  float sv = p;
#pragma unroll
  for (int o = 32; o > 0; o >>= 1) sv += __shfl_down(sv, o, 64);
  if (lane == 0) red[4 + wv] = sv;
  __syncthreads();
  float denom = red[4] + red[5] + red[6] + red[7];

  // ctx[d] = sum_k sc[k] * v[k,d] / denom; threads split 4 chunks of 64 keys
  int d = tid & 63, ch = tid >> 6;
  const float* vb = v + (size_t)bb * kS * kH + hh * kDH + d;
  float acc = 0.f;
  for (int kk = ch * 64; kk < ch * 64 + 64; kk++) acc += sc[kk] * vb[(size_t)kk * kH];
  part[tid] = acc;
  __syncthreads();
  if (tid < 64) {
    float r = part[tid] + part[64 + tid] + part[128 + tid] + part[192 + tid];
    ctx[(size_t)(bb * kS + qi) * kH + hh * kDH + tid] = r / denom;
  }
}

// ---------------------------------------------------------------------------
// Emissions: em[tok,c] = h[tok,:] @ cls_w[:,c] + cls_b[c]   (N=9)
// ---------------------------------------------------------------------------
__global__ __launch_bounds__(256) void emis_kernel(
    const float* __restrict__ h, const float* __restrict__ cw,
    const float* __restrict__ cb, float* __restrict__ em) {
  int idx = blockIdx.x * 256 + threadIdx.x;
  if (idx >= kM * kC) return;
  int tok = idx / kC, c = idx % kC;
  float acc = cb[c];
  for (int d = 0; d < kH; d++) acc += h[(size_t)tok * kH + d] * cw[d * kC + c];
  em[idx] = acc;
}

// ---------------------------------------------------------------------------
// CRF: numerator, forward algorithm (log-space), loss. One block, 128 threads.
// ---------------------------------------------------------------------------
__global__ __launch_bounds__(128) void crf_kernel(
    const float* __restrict__ em, const int* __restrict__ target,
    const float* __restrict__ start_, const float* __restrict__ end_,
    const float* __restrict__ trans_, float* __restrict__ out) {
  __shared__ float trans[kC][kC];
  __shared__ float stv[kC], env[kC];
  __shared__ float alpha[2][kB][kC];
  __shared__ float numden[kB];
  int tid = threadIdx.x;
  if (tid < kC * kC) trans[tid / kC][tid % kC] = trans_[tid];
  if (tid < kC) { stv[tid] = start_[tid]; env[tid] = end_[tid]; }
  __syncthreads();

  int bb = tid / kC, c = tid % kC;
  if (tid < kB * kC) alpha[0][bb][c] = stv[c] + em[(size_t)(bb * kS) * kC + c];
  __syncthreads();

  int cur = 0;
  for (int i = 1; i < kS; i++) {
    if (tid < kB * kC) {
      float mvv = -1e30f;
#pragma unroll
      for (int p = 0; p < kC; p++) mvv = fmaxf(mvv, alpha[cur][bb][p] + trans[p][c]);
      float sum = 0.f;
#pragma unroll
      for (int p = 0; p < kC; p++) sum += expf(alpha[cur][bb][p] + trans[p][c] - mvv);
      float nxt = mvv + logf(sum) + em[(size_t)(bb * kS + i) * kC + c];
      bool msk = target[bb * kS + i] > -1;
      alpha[1 - cur][bb][c] = msk ? nxt : alpha[cur][bb][c];
    }
    cur = 1 - cur;
    __syncthreads();
  }

  if (tid < kB) {
    // denominator: logsumexp(alpha + end)
    float mvv = -1e30f;
    for (int cc = 0; cc < kC; cc++) mvv = fmaxf(mvv, alpha[cur][tid][cc] + env[cc]);
    float sum = 0.f;
    for (int cc = 0; cc < kC; cc++) sum += expf(alpha[cur][tid][cc] + env[cc] - mvv);
    float den = mvv + logf(sum);
    // numerator along the gold path
    const int* tg = target + tid * kS;
    int t0 = tg[0] > -1 ? tg[0] : 0;
    float num = stv[t0] + em[(size_t)(tid * kS) * kC + t0];
    int last = t0;
    for (int i = 1; i < kS; i++) {
      int ti = tg[i];
      if (ti > -1) {
        int tp = tg[i - 1] > -1 ? tg[i - 1] : 0;
        num += trans[tp][ti] + em[(size_t)(tid * kS + i) * kC + ti];
        last = ti;
      }
    }
    num += env[last];
    numden[tid] = num - den;
  }
  __syncthreads();
  if (tid == 0) {
    float s = 0.f;
    for (int i = 0; i < kB; i++) s += numden[i];
    out[0] = -s / kB;   // fp32 scalar output
  }
}

// ---------------------------------------------------------------------------
extern "C" void kernel_launch(void* const* d_in, const int* in_sizes, int n_in,
                              void* d_out, int out_size, void* d_ws, size_t ws_size,
                              hipStream_t stream) {
  const int* x      = (const int*)d_in[0];
  const int* target = (const int*)d_in[1];
  const float* word_emb   = (const float*)d_in[2];
  const float* pos_emb    = (const float*)d_in[3];
  const float* type_emb   = (const float*)d_in[4];
  const float* emb_ln_w   = (const float*)d_in[5];
  const float* emb_ln_b   = (const float*)d_in[6];
  const float* qkv_w      = (const float*)d_in[7];
  const float* qkv_b      = (const float*)d_in[8];
  const float* attn_out_w = (const float*)d_in[9];
  const float* attn_out_b = (const float*)d_in[10];
  const float* attn_ln_w  = (const float*)d_in[11];
  const float* attn_ln_b  = (const float*)d_in[12];
  const float* ffn_w1     = (const float*)d_in[13];
  const float* ffn_b1     = (const float*)d_in[14];
  const float* ffn_w2     = (const float*)d_in[15];
  const float* ffn_b2     = (const float*)d_in[16];
  const float* ffn_ln_w   = (const float*)d_in[17];
  const float* ffn_ln_b   = (const float*)d_in[18];
  const float* cls_w      = (const float*)d_in[19];
  const float* cls_b      = (const float*)d_in[20];
  const float* crf_start  = (const float*)d_in[21];
  const float* crf_end    = (const float*)d_in[22];
  const float* crf_trans  = (const float*)d_in[23];

  // Workspace layout (fp32, aliased): ~37.8 MB total.
  //   h  : [M,H]
  //   R  : max(4*[M,H], [M,FF]) = 6,291,456 floats (exactly equal)
  //        attention phase: q=R, k=R+MH, v=R+2MH, tb=R+3MH
  //        ffn phase:       f1=R (q/k/v/tb dead by then)
  //   o2 : [M,H]
  //   em : [M,C]
  constexpr size_t MH  = (size_t)kM * kH;        // 1,572,864
  constexpr size_t RSZ = (size_t)kM * kFF;       // 6,291,456
  float* ws = (float*)d_ws;
  float* h  = ws;
  float* R  = ws + MH;
  float* o2 = R + RSZ;
  float* em = o2 + MH;

  float* qb = R;
  float* kb = R + MH;
  float* vb = R + 2 * MH;
  float* tb = R + 3 * MH;
  float* f1 = R;

  embed_kernel<<<kM, 256, 0, stream>>>(x, word_emb, pos_emb, type_emb, h);
  addln_kernel<<<kM, 256, 0, stream>>>(h, nullptr, emb_ln_w, emb_ln_b, h);

  for (int l = 0; l < kNL; l++) {
    const float* Wq = qkv_w + (size_t)l * 3 * kH * kH;
    gemm_kernel<0><<<dim3(kH / 64, kM / 64), 256, 0, stream>>>(
        h, Wq, qkv_b + l * 3 * kH, qb, kM, kH, kH);
    gemm_kernel<0><<<dim3(kH / 64, kM / 64), 256, 0, stream>>>(
        h, Wq + (size_t)kH * kH, qkv_b + l * 3 * kH + kH, kb, kM, kH, kH);
    gemm_kernel<0><<<dim3(kH / 64, kM / 64), 256, 0, stream>>>(
        h, Wq + (size_t)2 * kH * kH, qkv_b + l * 3 * kH + 2 * kH, vb, kM, kH, kH);
    attn_kernel<<<dim3(kS, kNH, kB), 256, 0, stream>>>(qb, kb, vb, tb);
    gemm_kernel<0><<<dim3(kH / 64, kM / 64), 256, 0, stream>>>(
        tb, attn_out_w + (size_t)l * kH * kH, attn_out_b + l * kH, o2, kM, kH, kH);
    addln_kernel<<<kM, 256, 0, stream>>>(h, o2, attn_ln_w + l * kH, attn_ln_b + l * kH, h);
    gemm_kernel<1><<<dim3(kFF / 64, kM / 64), 256, 0, stream>>>(
        h, ffn_w1 + (size_t)l * kH * kFF, ffn_b1 + l * kFF, f1, kM, kFF, kH);
    gemm_kernel<0><<<dim3(kH / 64, kM / 64), 256, 0, stream>>>(
        f1, ffn_w2 + (size_t)l * kFF * kH, ffn_b2 + l * kH, o2, kM, kH, kFF);
    addln_kernel<<<kM, 256, 0, stream>>>(h, o2, ffn_ln_w + l * kH, ffn_ln_b + l * kH, h);
  }

  emis_kernel<<<(kM * kC + 255) / 256, 256, 0, stream>>>(h, cls_w, cls_b, em);
  crf_kernel<<<1, 128, 0, stream>>>(em, target, crf_start, crf_end, crf_trans,
                                    (float*)d_out);
}